// Round 14
// baseline (298.370 us; speedup 1.0000x reference)
//
#include <hip/hip_runtime.h>
#include <math.h>

#define H  64
#define F  32
#define NB 4      // batch columns per block
#define NT 512    // 8 waves: 0-3 = layer0, 4-7 = layer1 (wave-specialized)
#define HS 80     // h row stride (shorts): 160B -> 2-way banks max (free)

typedef __attribute__((ext_vector_type(8))) short   s8v;   // 8 bf16 payload
typedef __attribute__((ext_vector_type(8))) __bf16  bf8v;  // MFMA operand type
typedef __attribute__((ext_vector_type(4))) float   f4v;   // MFMA accumulator

__device__ __forceinline__ unsigned short f2bf(float x) {   // weight init only
    unsigned u = __builtin_bit_cast(unsigned, x);
    u += 0x7FFFu + ((u >> 16) & 1u);          // RNE
    return (unsigned short)(u >> 16);
}
// HW packed f32->bf16 RNE convert (1 instr)
__device__ __forceinline__ unsigned cvtpk(float a, float b) {
    unsigned r;
    asm("v_cvt_pk_bf16_f32 %0, %1, %2" : "=v"(r) : "v"(a), "v"(b));
    return r;
}
// D = A*B + C ; A = activations (rows = batch-dup), B = weights (cols = gate rows)
__device__ __forceinline__ f4v mfma_(s8v a, s8v b, f4v c) {
    return __builtin_amdgcn_mfma_f32_16x16x32_bf16(
        __builtin_bit_cast(bf8v, a), __builtin_bit_cast(bf8v, b), c, 0, 0, 0);
}
__device__ __forceinline__ float sig_(float x) {
    return __builtin_amdgcn_rcpf(1.0f + __expf(-x));
}
__device__ __forceinline__ float tanh_(float x) {
    return 1.0f - 2.0f * __builtin_amdgcn_rcpf(1.0f + __expf(2.0f * x));
}
// LDS-flush + raw barrier: does NOT drain vmcnt (x loads stay in flight)
__device__ __forceinline__ void bar_lds() {
    asm volatile("s_waitcnt lgkmcnt(0)" ::: "memory");
    __builtin_amdgcn_s_barrier();
}
// Load an 8-wide B-fragment slice of a weight row, bf16-hi only.
__device__ __forceinline__ s8v load_hi(const float* __restrict__ Wrow, int koff) {
    s8v hi;
    #pragma unroll
    for (int i = 0; i < 8; ++i) hi[i] = (short)f2bf(Wrow[koff + i]);
    return hi;
}
// Build a bf16 A-fragment from 8 in-register floats.
__device__ __forceinline__ s8v xfrag(const float4& a, const float4& b) {
    s8v r; unsigned* ru = (unsigned*)&r;
    ru[0] = cvtpk(a.x, a.y); ru[1] = cvtpk(a.z, a.w);
    ru[2] = cvtpk(b.x, b.y); ru[3] = cvtpk(b.z, b.w);
    return r;
}

__global__ __launch_bounds__(NT, 2)
void lstm_v14(const float* __restrict__ x,     // [B,T,F]
              const float* __restrict__ Wih0,  // [4H,F]
              const float* __restrict__ Whh0,  // [4H,H]
              const float* __restrict__ bih0,
              const float* __restrict__ bhh0,
              const float* __restrict__ Wih1,  // [4H,H]
              const float* __restrict__ Whh1,  // [4H,H]
              const float* __restrict__ bih1,
              const float* __restrict__ bhh1,
              const float* __restrict__ fcw,   // [1,H]
              const float* __restrict__ fcb,   // [1]
              float* __restrict__ out,         // [B]
              int T, int B)
{
    const int tid  = threadIdx.x;
    const int w    = tid >> 6;          // 0..7
    const int wl   = w & 3;             // wave within its layer group
    const bool isL0 = (w < 4);
    const int lane = tid & 63;
    const int j    = lane & 15;         // MFMA col: unit within wave's 16-unit group
    const int hi4  = lane >> 4;         // k-slice for fragments; batch for pointwise
    const int bm   = j >> 2;            // A-fragment batch row map  pi(m) = m>>2
    const int u    = 16 * wl + j;       // this lane's hidden unit
    const int b0   = blockIdx.x * NB;

    __shared__ alignas(16) unsigned short h0[2][NB][HS];   // bf16 acts
    __shared__ alignas(16) unsigned short h1[2][NB][HS];
    __shared__ float part[4][64];
    __shared__ int cnt;                 // L1-group spin counter

    for (int i = tid; i < 2 * NB * HS; i += NT) {
        (&h0[0][0][0])[i] = 0;
        (&h1[0][0][0])[i] = 0;
    }
    if (tid == 0) cnt = 0;

    if (isL0) {
        // ================= LAYER-0 WAVES =================
        s8v wxh[4];          // Wih0 hi
        s8v whh[4][2];       // Whh0 hi
        float bias[4];
        #pragma unroll
        for (int g = 0; g < 4; ++g) {
            const int R = 64 * g + 16 * wl + j;
            wxh[g] = load_hi(&Wih0[R * F], 8 * hi4);
            whh[g][0] = load_hi(&Whh0[R * H], 8 * hi4);
            whh[g][1] = load_hi(&Whh0[R * H], 32 + 8 * hi4);
            bias[g] = bih0[R] + bhh0[R];
        }
        // x pipeline: xf pre-built for the UPCOMING step; regs hold rows ~3 ahead
        const float* xrow = x + ((size_t)(b0 + bm) * T) * F + 8 * hi4;
        const int tmax = T - 1;
        float4 p0 = *(const float4*)(xrow);
        float4 p1 = *(const float4*)(xrow + 4);
        s8v xf = xfrag(p0, p1);                               // x(0)
        const size_t o1 = (size_t)((1 < tmax) ? 1 : tmax) * F;
        const size_t o2 = (size_t)((2 < tmax) ? 2 : tmax) * F;
        float4 xB0 = *(const float4*)(xrow + o1), xB1 = *(const float4*)(xrow + o1 + 4); // x(1)
        float4 xA0 = *(const float4*)(xrow + o2), xA1 = *(const float4*)(xrow + o2 + 4); // x(2)

        __syncthreads();   // prolog barrier (h zeros, cnt=0 visible)

        float c = 0.f;
        auto stepL0 = [&](int s, int par, float4& n0, float4& n1) {
            if (s < T) {
                const s8v hf0 = *(const s8v*)&h0[par ^ 1][bm][8 * hi4];
                const s8v hf1 = *(const s8v*)&h0[par ^ 1][bm][8 * (4 + hi4)];
                __builtin_amdgcn_s_setprio(1);
                f4v a[4], b[4];
                #pragma unroll
                for (int g = 0; g < 4; ++g) {
                    f4v av = {bias[g], bias[g], bias[g], bias[g]};
                    a[g] = mfma_(xf, wxh[g], av);     // xf register-ready: issues in ds shadow
                    f4v bv = {0.f, 0.f, 0.f, 0.f};
                    bv = mfma_(hf0, whh[g][0], bv);
                    b[g] = mfma_(hf1, whh[g][1], bv);
                }
                __builtin_amdgcn_s_setprio(0);
                const float gi = sig_(a[0][0] + b[0][0]);
                const float gf = sig_(a[1][0] + b[1][0]);
                const float gg = tanh_(a[2][0] + b[2][0]);
                const float go = sig_(a[3][0] + b[3][0]);
                c = gf * c + gi * gg;
                const float hv = go * tanh_(c);
                h0[par][hi4][u] = (unsigned short)cvtpk(hv, hv);
                // pre-build x(s+1) fragment; refill regs with x(s+3)
                xf = xfrag(n0, n1);
                const size_t tld = (size_t)((s + 3 < tmax) ? (s + 3) : tmax) * F;
                n0 = *(const float4*)(xrow + tld);
                n1 = *(const float4*)(xrow + tld + 4);
            }
            bar_lds();
        };

        #pragma unroll 1
        for (int s = 0; s < T + 2; s += 2) {   // T even
            stepL0(s,     0, xB0, xB1);
            stepL0(s + 1, 1, xA0, xA1);
        }
    } else {
        // ================= LAYER-1 WAVES (phase-inverted, spin-synced) ==========
        s8v wgh[4][2];       // Wih1 hi
        s8v whh[4][2];       // Whh1 hi
        float bias[4];
        #pragma unroll
        for (int g = 0; g < 4; ++g) {
            const int R = 64 * g + 16 * wl + j;
            wgh[g][0] = load_hi(&Wih1[R * H], 8 * hi4);
            wgh[g][1] = load_hi(&Wih1[R * H], 32 + 8 * hi4);
            whh[g][0] = load_hi(&Whh1[R * H], 8 * hi4);
            whh[g][1] = load_hi(&Whh1[R * H], 32 + 8 * hi4);
            bias[g] = bih1[R] + bhh1[R];
        }
        const float fcwr = fcw[u];
        __syncthreads();   // prolog barrier

        float c = 0.f;
        f4v accP[4], accQ[4];   // ping-pong: acc(s-1) built this iter, acc(s-2) consumed

        auto stepL1 = [&](int s, int par, f4v (&aN)[4], f4v (&aO)[4]) {
            // --- MFMA-A(t=s-1): bias + Wih1 @ h0(s-1) ---
            if (s >= 1 && s <= T) {
                const s8v gf0 = *(const s8v*)&h0[par ^ 1][bm][8 * hi4];
                const s8v gf1 = *(const s8v*)&h0[par ^ 1][bm][8 * (4 + hi4)];
                __builtin_amdgcn_s_setprio(1);
                #pragma unroll
                for (int g = 0; g < 4; ++g) {
                    f4v av = {bias[g], bias[g], bias[g], bias[g]};
                    av = mfma_(gf0, wgh[g][0], av);
                    aN[g] = mfma_(gf1, wgh[g][1], av);
                }
                __builtin_amdgcn_s_setprio(0);
            }
            // --- pointwise(t=s-2) from saved accumulators; write h1(s-2) ---
            if (s >= 2) {
                const float gi = sig_(aO[0][0]);
                const float gf = sig_(aO[1][0]);
                const float gg = tanh_(aO[2][0]);
                const float go = sig_(aO[3][0]);
                c = gf * c + gi * gg;
                const float hv = go * tanh_(c);
                if (s <= T) {
                    h1[par][hi4][u] = (unsigned short)cvtpk(hv, hv);
                } else {
                    part[wl][lane] = hv * fcwr;   // t = T-1: fc-head partial
                }
            }
            // --- L1-group spin-sync: h1(s-2) visible to all L1 waves ---
            if (s >= 2 && s <= T) {
                asm volatile("s_waitcnt lgkmcnt(0)" ::: "memory");
                if (lane == 0) atomicAdd(&cnt, 1);
                const int tgt = 4 * (s - 1);
                volatile int* p = &cnt;
                while (*p < tgt) {}
                __builtin_amdgcn_sched_barrier(0);
                asm volatile("" ::: "memory");
            }
            // --- MFMA-B(t=s-1): += Whh1 @ h1(s-2)  (zeros for s==1) ---
            if (s >= 1 && s <= T) {
                const s8v hf0 = *(const s8v*)&h1[par][bm][8 * hi4];
                const s8v hf1 = *(const s8v*)&h1[par][bm][8 * (4 + hi4)];
                __builtin_amdgcn_s_setprio(1);
                #pragma unroll
                for (int g = 0; g < 4; ++g) {
                    aN[g] = mfma_(hf0, whh[g][0], aN[g]);
                    aN[g] = mfma_(hf1, whh[g][1], aN[g]);
                }
                __builtin_amdgcn_s_setprio(0);
            }
            bar_lds();
        };

        #pragma unroll 1
        for (int s = 0; s < T + 2; s += 2) {   // T even
            stepL1(s,     0, accP, accQ);
            stepL1(s + 1, 1, accQ, accP);
        }
    }

    __syncthreads();   // part[] visible

    // ---- fc head: out[b] = sum_u h1(T-1)[b][u]*fcw[u] + fcb ----
    if (tid < 64) {
        float v = part[0][lane] + part[1][lane] + part[2][lane] + part[3][lane];
        v += __shfl_xor(v, 1);
        v += __shfl_xor(v, 2);
        v += __shfl_xor(v, 4);
        v += __shfl_xor(v, 8);
        if (j == 0) out[b0 + hi4] = v + fcb[0];
    }
}

extern "C" void kernel_launch(void* const* d_in, const int* in_sizes, int n_in,
                              void* d_out, int out_size, void* d_ws, size_t ws_size,
                              hipStream_t stream) {
    const float* x    = (const float*)d_in[0];
    const float* Wih0 = (const float*)d_in[1];
    const float* Whh0 = (const float*)d_in[2];
    const float* bih0 = (const float*)d_in[3];
    const float* bhh0 = (const float*)d_in[4];
    const float* Wih1 = (const float*)d_in[5];
    const float* Whh1 = (const float*)d_in[6];
    const float* bih1 = (const float*)d_in[7];
    const float* bhh1 = (const float*)d_in[8];
    const float* fcw  = (const float*)d_in[9];
    const float* fcb  = (const float*)d_in[10];
    float* out = (float*)d_out;

    const int B = out_size;                 // 1024
    const int T = in_sizes[0] / (B * F);    // 512

    dim3 grid(B / NB), block(NT);
    hipLaunchKernelGGL(lstm_v14, grid, block, 0, stream,
                       x, Wih0, Whh0, bih0, bhh0,
                       Wih1, Whh1, bih1, bhh1, fcw, fcb,
                       out, T, B);
}

// Round 15
// 224.001 us; speedup vs baseline: 1.3320x; 1.3320x over previous
//
#include <hip/hip_runtime.h>
#include <math.h>

#define H  64
#define F  32
#define NB 4      // batch columns per block
#define NT 512    // 8 waves: 0-3 = layer0, 4-7 = layer1 (wave-specialized)
#define HS 80     // h row stride (shorts): 160B -> 2-way banks max (free)

typedef __attribute__((ext_vector_type(8))) short   s8v;   // 8 bf16 payload
typedef __attribute__((ext_vector_type(8))) __bf16  bf8v;  // MFMA operand type
typedef __attribute__((ext_vector_type(4))) float   f4v;   // MFMA accumulator

__device__ __forceinline__ unsigned short f2bf(float x) {   // weight init only
    unsigned u = __builtin_bit_cast(unsigned, x);
    u += 0x7FFFu + ((u >> 16) & 1u);          // RNE
    return (unsigned short)(u >> 16);
}
// HW packed f32->bf16 RNE convert (1 instr)
__device__ __forceinline__ unsigned cvtpk(float a, float b) {
    unsigned r;
    asm("v_cvt_pk_bf16_f32 %0, %1, %2" : "=v"(r) : "v"(a), "v"(b));
    return r;
}
// D = A*B + C ; A = activations (rows = batch-dup), B = weights (cols = gate rows)
__device__ __forceinline__ f4v mfma_(s8v a, s8v b, f4v c) {
    return __builtin_amdgcn_mfma_f32_16x16x32_bf16(
        __builtin_bit_cast(bf8v, a), __builtin_bit_cast(bf8v, b), c, 0, 0, 0);
}
__device__ __forceinline__ float sig_(float x) {
    return __builtin_amdgcn_rcpf(1.0f + __expf(-x));
}
__device__ __forceinline__ float tanh_(float x) {
    return 1.0f - 2.0f * __builtin_amdgcn_rcpf(1.0f + __expf(2.0f * x));
}
// LDS-flush + raw barrier: does NOT drain vmcnt (x loads stay in flight)
__device__ __forceinline__ void bar_lds() {
    asm volatile("s_waitcnt lgkmcnt(0)" ::: "memory");
    __builtin_amdgcn_s_barrier();
}
// Load an 8-wide B-fragment slice of a weight row, bf16-hi only.
__device__ __forceinline__ s8v load_hi(const float* __restrict__ Wrow, int koff) {
    s8v hi;
    #pragma unroll
    for (int i = 0; i < 8; ++i) hi[i] = (short)f2bf(Wrow[koff + i]);
    return hi;
}
// Build a bf16 A-fragment from 8 in-register floats.
__device__ __forceinline__ s8v xfrag(const float4& a, const float4& b) {
    s8v r; unsigned* ru = (unsigned*)&r;
    ru[0] = cvtpk(a.x, a.y); ru[1] = cvtpk(a.z, a.w);
    ru[2] = cvtpk(b.x, b.y); ru[3] = cvtpk(b.z, b.w);
    return r;
}

__global__ __launch_bounds__(NT, 2)
void lstm_v15(const float* __restrict__ x,     // [B,T,F]
              const float* __restrict__ Wih0,  // [4H,F]
              const float* __restrict__ Whh0,  // [4H,H]
              const float* __restrict__ bih0,
              const float* __restrict__ bhh0,
              const float* __restrict__ Wih1,  // [4H,H]
              const float* __restrict__ Whh1,  // [4H,H]
              const float* __restrict__ bih1,
              const float* __restrict__ bhh1,
              const float* __restrict__ fcw,   // [1,H]
              const float* __restrict__ fcb,   // [1]
              float* __restrict__ out,         // [B]
              int T, int B)
{
    const int tid  = threadIdx.x;
    const int w    = tid >> 6;          // 0..7
    const int wl   = w & 3;             // wave within its layer group
    const bool isL0 = (w < 4);
    const int lane = tid & 63;
    const int j    = lane & 15;         // MFMA col: unit within wave's 16-unit group
    const int hi4  = lane >> 4;         // k-slice for fragments; batch for pointwise
    const int bm   = j >> 2;            // A-fragment batch row map  pi(m) = m>>2
    const int u    = 16 * wl + j;       // this lane's hidden unit
    const int b0   = blockIdx.x * NB;

    __shared__ alignas(16) unsigned short h0[2][NB][HS];   // bf16 acts
    __shared__ alignas(16) unsigned short h1[2][NB][HS];
    __shared__ float part[4][64];

    for (int i = tid; i < 2 * NB * HS; i += NT) {
        (&h0[0][0][0])[i] = 0;
        (&h1[0][0][0])[i] = 0;
    }

    if (isL0) {
        // ================= LAYER-0 WAVES (v14 structure) =================
        s8v wxh[4];          // Wih0 hi
        s8v whh[4][2];       // Whh0 hi
        float bias[4];
        #pragma unroll
        for (int g = 0; g < 4; ++g) {
            const int R = 64 * g + 16 * wl + j;
            wxh[g] = load_hi(&Wih0[R * F], 8 * hi4);
            whh[g][0] = load_hi(&Whh0[R * H], 8 * hi4);
            whh[g][1] = load_hi(&Whh0[R * H], 32 + 8 * hi4);
            bias[g] = bih0[R] + bhh0[R];
        }
        // x pipeline: xf pre-built for the UPCOMING step; regs hold rows ~3 ahead
        const float* xrow = x + ((size_t)(b0 + bm) * T) * F + 8 * hi4;
        const int tmax = T - 1;
        float4 p0 = *(const float4*)(xrow);
        float4 p1 = *(const float4*)(xrow + 4);
        s8v xf = xfrag(p0, p1);                               // x(0)
        const size_t o1 = (size_t)((1 < tmax) ? 1 : tmax) * F;
        const size_t o2 = (size_t)((2 < tmax) ? 2 : tmax) * F;
        float4 xB0 = *(const float4*)(xrow + o1), xB1 = *(const float4*)(xrow + o1 + 4); // x(1)
        float4 xA0 = *(const float4*)(xrow + o2), xA1 = *(const float4*)(xrow + o2 + 4); // x(2)

        __syncthreads();   // prolog barrier (h zeros visible)

        float c = 0.f;
        auto stepL0 = [&](int s, int par, float4& n0, float4& n1) {
            if (s < T) {
                const s8v hf0 = *(const s8v*)&h0[par ^ 1][bm][8 * hi4];
                const s8v hf1 = *(const s8v*)&h0[par ^ 1][bm][8 * (4 + hi4)];
                __builtin_amdgcn_s_setprio(1);
                f4v a[4], b[4];
                #pragma unroll
                for (int g = 0; g < 4; ++g) {
                    f4v av = {bias[g], bias[g], bias[g], bias[g]};
                    a[g] = mfma_(xf, wxh[g], av);     // xf register-ready: issues in ds shadow
                    f4v bv = {0.f, 0.f, 0.f, 0.f};
                    bv = mfma_(hf0, whh[g][0], bv);
                    b[g] = mfma_(hf1, whh[g][1], bv);
                }
                __builtin_amdgcn_s_setprio(0);
                const float gi = sig_(a[0][0] + b[0][0]);
                const float gf = sig_(a[1][0] + b[1][0]);
                const float gg = tanh_(a[2][0] + b[2][0]);
                const float go = sig_(a[3][0] + b[3][0]);
                c = gf * c + gi * gg;
                const float hv = go * tanh_(c);
                h0[par][hi4][u] = (unsigned short)cvtpk(hv, hv);
                // pre-build x(s+1) fragment; refill regs with x(s+3)
                xf = xfrag(n0, n1);
                const size_t tld = (size_t)((s + 3 < tmax) ? (s + 3) : tmax) * F;
                n0 = *(const float4*)(xrow + tld);
                n1 = *(const float4*)(xrow + tld + 4);
            }
            bar_lds();
        };

        #pragma unroll 1
        for (int s = 0; s < T + 2; s += 2) {   // T even -> T+2 barriers
            stepL0(s,     0, xB0, xB1);
            stepL0(s + 1, 1, xA0, xA1);
        }
    } else {
        // ========== LAYER-1 WAVES: deferred-B pipeline, zero extra sync ==========
        // iter s: accB(t=s-2) <- h1(s-3)[stable]; accA(t=s-1) <- h0(s-1)[stable];
        //         pw(t=s-2) = f(accA_old + accB_fresh) -> h1(s-2); one barrier.
        s8v wgh[4][2];       // Wih1 hi
        s8v whh[4][2];       // Whh1 hi
        float bias[4];
        #pragma unroll
        for (int g = 0; g < 4; ++g) {
            const int R = 64 * g + 16 * wl + j;
            wgh[g][0] = load_hi(&Wih1[R * H], 8 * hi4);
            wgh[g][1] = load_hi(&Wih1[R * H], 32 + 8 * hi4);
            whh[g][0] = load_hi(&Whh1[R * H], 8 * hi4);
            whh[g][1] = load_hi(&Whh1[R * H], 32 + 8 * hi4);
            bias[g] = bih1[R] + bhh1[R];
        }
        const float fcwr = fcw[u];
        __syncthreads();   // prolog barrier

        float c = 0.f;
        f4v accP[4], accQ[4];   // accA ping-pong: aNew built this iter, aOld consumed

        auto stepL1 = [&](int s, int par, f4v (&aNew)[4], f4v (&aOld)[4]) {
            // --- accB(t=s-2) from h1(s-3) [buf par^1, stable since iter s-1] ---
            f4v accB[4];
            const bool doB = (s >= 2 && s <= T + 1);
            const bool doA = (s >= 1 && s <= T);
            if (doB || doA) __builtin_amdgcn_s_setprio(1);
            if (doB) {
                const s8v hf0 = *(const s8v*)&h1[par ^ 1][bm][8 * hi4];
                const s8v hf1 = *(const s8v*)&h1[par ^ 1][bm][8 * (4 + hi4)];
                #pragma unroll
                for (int g = 0; g < 4; ++g) {
                    f4v bv = {0.f, 0.f, 0.f, 0.f};
                    bv = mfma_(hf0, whh[g][0], bv);
                    accB[g] = mfma_(hf1, whh[g][1], bv);
                }
            }
            // --- accA(t=s-1) from h0(s-1) [buf par^1, stable] ---
            if (doA) {
                const s8v gf0 = *(const s8v*)&h0[par ^ 1][bm][8 * hi4];
                const s8v gf1 = *(const s8v*)&h0[par ^ 1][bm][8 * (4 + hi4)];
                #pragma unroll
                for (int g = 0; g < 4; ++g) {
                    f4v av = {bias[g], bias[g], bias[g], bias[g]};
                    av = mfma_(gf0, wgh[g][0], av);
                    aNew[g] = mfma_(gf1, wgh[g][1], av);
                }
            }
            if (doB || doA) __builtin_amdgcn_s_setprio(0);
            // --- pointwise(t=s-2): overlaps accA MFMAs still in the pipe ---
            if (s >= 2) {
                const float gi = sig_(aOld[0][0] + accB[0][0]);
                const float gf = sig_(aOld[1][0] + accB[1][0]);
                const float gg = tanh_(aOld[2][0] + accB[2][0]);
                const float go = sig_(aOld[3][0] + accB[3][0]);
                c = gf * c + gi * gg;
                const float hv = go * tanh_(c);
                if (s <= T) {
                    h1[par][hi4][u] = (unsigned short)cvtpk(hv, hv);   // h1(s-2)
                } else {
                    part[wl][lane] = hv * fcwr;   // t = T-1: fc-head partial
                }
            }
            bar_lds();
        };

        #pragma unroll 1
        for (int s = 0; s < T + 2; s += 2) {   // T even -> s = 0 .. T+1, T+2 barriers
            stepL1(s,     0, accP, accQ);
            stepL1(s + 1, 1, accQ, accP);
        }
    }

    __syncthreads();   // part[] visible

    // ---- fc head: out[b] = sum_u h1(T-1)[b][u]*fcw[u] + fcb ----
    if (tid < 64) {
        float v = part[0][lane] + part[1][lane] + part[2][lane] + part[3][lane];
        v += __shfl_xor(v, 1);
        v += __shfl_xor(v, 2);
        v += __shfl_xor(v, 4);
        v += __shfl_xor(v, 8);
        if (j == 0) out[b0 + hi4] = v + fcb[0];
    }
}

extern "C" void kernel_launch(void* const* d_in, const int* in_sizes, int n_in,
                              void* d_out, int out_size, void* d_ws, size_t ws_size,
                              hipStream_t stream) {
    const float* x    = (const float*)d_in[0];
    const float* Wih0 = (const float*)d_in[1];
    const float* Whh0 = (const float*)d_in[2];
    const float* bih0 = (const float*)d_in[3];
    const float* bhh0 = (const float*)d_in[4];
    const float* Wih1 = (const float*)d_in[5];
    const float* Whh1 = (const float*)d_in[6];
    const float* bih1 = (const float*)d_in[7];
    const float* bhh1 = (const float*)d_in[8];
    const float* fcw  = (const float*)d_in[9];
    const float* fcb  = (const float*)d_in[10];
    float* out = (float*)d_out;

    const int B = out_size;                 // 1024
    const int T = in_sizes[0] / (B * F);    // 512

    dim3 grid(B / NB), block(NT);
    hipLaunchKernelGGL(lstm_v15, grid, block, 0, stream,
                       x, Wih0, Whh0, bih0, bhh0,
                       Wih1, Whh1, bih1, bhh1, fcw, fcb,
                       out, T, B);
}

// Round 16
// 210.090 us; speedup vs baseline: 1.4202x; 1.0662x over previous
//
#include <hip/hip_runtime.h>
#include <math.h>

#define H  64
#define F  32
#define NB 4      // batch columns per block
#define NT 512    // 8 waves: 0-3 = layer0, 4-7 = layer1 (wave-specialized)
#define HS 80     // h row stride (shorts): 160B -> 2-way banks max (free)

typedef __attribute__((ext_vector_type(8))) short   s8v;   // 8 bf16 payload
typedef __attribute__((ext_vector_type(8))) __bf16  bf8v;  // MFMA operand type
typedef __attribute__((ext_vector_type(4))) float   f4v;   // MFMA accumulator

__device__ __forceinline__ unsigned short f2bf(float x) {   // weight init only
    unsigned u = __builtin_bit_cast(unsigned, x);
    u += 0x7FFFu + ((u >> 16) & 1u);          // RNE
    return (unsigned short)(u >> 16);
}
// HW packed f32->bf16 RNE convert (1 instr)
__device__ __forceinline__ unsigned cvtpk(float a, float b) {
    unsigned r;
    asm("v_cvt_pk_bf16_f32 %0, %1, %2" : "=v"(r) : "v"(a), "v"(b));
    return r;
}
// D = A*B + C ; A = activations (rows = batch-dup), B = weights (cols = gate rows)
__device__ __forceinline__ f4v mfma_(s8v a, s8v b, f4v c) {
    return __builtin_amdgcn_mfma_f32_16x16x32_bf16(
        __builtin_bit_cast(bf8v, a), __builtin_bit_cast(bf8v, b), c, 0, 0, 0);
}
__device__ __forceinline__ float sig_(float x) {
    return __builtin_amdgcn_rcpf(1.0f + __expf(-x));
}
__device__ __forceinline__ float tanh_(float x) {
    return 1.0f - 2.0f * __builtin_amdgcn_rcpf(1.0f + __expf(2.0f * x));
}
// LDS-flush + raw barrier: does NOT drain vmcnt (x loads stay in flight)
__device__ __forceinline__ void bar_lds() {
    asm volatile("s_waitcnt lgkmcnt(0)" ::: "memory");
    __builtin_amdgcn_s_barrier();
}

// Load an 8-wide B-fragment slice of a weight row, bf16-hi only.
__device__ __forceinline__ s8v load_hi(const float* __restrict__ Wrow, int koff) {
    s8v hi;
    #pragma unroll
    for (int i = 0; i < 8; ++i) hi[i] = (short)f2bf(Wrow[koff + i]);
    return hi;
}

__global__ __launch_bounds__(NT, 2)
void lstm_v16(const float* __restrict__ x,     // [B,T,F]
              const float* __restrict__ Wih0,  // [4H,F]
              const float* __restrict__ Whh0,  // [4H,H]
              const float* __restrict__ bih0,
              const float* __restrict__ bhh0,
              const float* __restrict__ Wih1,  // [4H,H]
              const float* __restrict__ Whh1,  // [4H,H]
              const float* __restrict__ bih1,
              const float* __restrict__ bhh1,
              const float* __restrict__ fcw,   // [1,H]
              const float* __restrict__ fcb,   // [1]
              float* __restrict__ out,         // [B]
              int T, int B)
{
    const int tid  = threadIdx.x;
    const int w    = tid >> 6;          // 0..7
    const int wl   = w & 3;             // wave within its layer group
    const bool isL0 = (w < 4);
    const int lane = tid & 63;
    const int j    = lane & 15;         // MFMA col: unit within wave's 16-unit group
    const int hi4  = lane >> 4;         // k-slice for fragments; batch for pointwise
    const int bm   = j >> 2;            // A-fragment batch row map  pi(m) = m>>2
    const int u    = 16 * wl + j;       // this lane's hidden unit
    const int b0   = blockIdx.x * NB;

    __shared__ alignas(16) unsigned short h0[2][NB][HS];
    __shared__ alignas(16) unsigned short h1[2][NB][HS];
    __shared__ float part[4][64];

    for (int i = tid; i < 2 * NB * HS; i += NT) {
        (&h0[0][0][0])[i] = 0;
        (&h1[0][0][0])[i] = 0;
    }

    if (isL0) {
        // ================= LAYER-0 WAVES =================
        s8v wxh[4];          // Wih0 hi
        s8v whh[4][2];       // Whh0 hi
        float bias[4];
        #pragma unroll
        for (int g = 0; g < 4; ++g) {
            const int R = 64 * g + 16 * wl + j;
            wxh[g] = load_hi(&Wih0[R * F], 8 * hi4);
            whh[g][0] = load_hi(&Whh0[R * H], 8 * hi4);
            whh[g][1] = load_hi(&Whh0[R * H], 32 + 8 * hi4);
            bias[g] = bih0[R] + bhh0[R];
        }
        // x direct-load: this lane's 8-float slice of its batch row
        const float* xrow = x + ((size_t)(b0 + bm) * T) * F + 8 * hi4;
        float4 xA0 = *(const float4*)(xrow);          // t=0
        float4 xA1 = *(const float4*)(xrow + 4);
        float4 xB0 = *(const float4*)(xrow + F);      // t=1
        float4 xB1 = *(const float4*)(xrow + F + 4);

        __syncthreads();   // prolog barrier (h zeros visible)

        float c = 0.f;
        auto stepL0 = [&](int s, int par, float4& xr0, float4& xr1) {
            // critical ds reads issue FIRST after the barrier
            const s8v hf0 = *(const s8v*)&h0[par ^ 1][bm][8 * hi4];
            const s8v hf1 = *(const s8v*)&h0[par ^ 1][bm][8 * (4 + hi4)];

            // x(s) fragment built in the ds-latency shadow (bit-identical bf16 RNE)
            s8v xf;
            unsigned* xfu = (unsigned*)&xf;
            xfu[0] = cvtpk(xr0.x, xr0.y);
            xfu[1] = cvtpk(xr0.z, xr0.w);
            xfu[2] = cvtpk(xr1.x, xr1.y);
            xfu[3] = cvtpk(xr1.z, xr1.w);
            // issue x(s+2) load into the same regs (consumed 2 steps later)
            const size_t tld = (size_t)((s + 2 < T) ? (s + 2) : (T - 1)) * F;
            xr0 = *(const float4*)(xrow + tld);
            xr1 = *(const float4*)(xrow + tld + 4);

            f4v a[4], b[4];
            __builtin_amdgcn_s_setprio(1);
            #pragma unroll
            for (int g = 0; g < 4; ++g) {
                f4v av = {bias[g], bias[g], bias[g], bias[g]};
                a[g] = mfma_(xf, wxh[g], av);         // register-ready: issues under lgkm
                f4v bv = {0.f, 0.f, 0.f, 0.f};
                bv = mfma_(hf0, whh[g][0], bv);
                b[g] = mfma_(hf1, whh[g][1], bv);
            }
            __builtin_amdgcn_s_setprio(0);
            const float gi = sig_(a[0][0] + b[0][0]);
            const float gf = sig_(a[1][0] + b[1][0]);
            const float gg = tanh_(a[2][0] + b[2][0]);
            const float go = sig_(a[3][0] + b[3][0]);
            c = gf * c + gi * gg;
            const float hv = go * tanh_(c);
            h0[par][hi4][u] = (unsigned short)cvtpk(hv, hv);
            bar_lds();
        };

        #pragma unroll 1
        for (int s = 0; s < T; s += 2) {       // T even
            stepL0(s,     0, xA0, xA1);
            stepL0(s + 1, 1, xB0, xB1);
        }
        bar_lds();   // tail step s=T: L0 idle (barrier count match)
    } else {
        // ================= LAYER-1 WAVES =================
        s8v wgh[4][2];       // Wih1 hi
        s8v whh[4][2];       // Whh1 hi
        float bias[4];
        #pragma unroll
        for (int g = 0; g < 4; ++g) {
            const int R = 64 * g + 16 * wl + j;
            wgh[g][0] = load_hi(&Wih1[R * H], 8 * hi4);
            wgh[g][1] = load_hi(&Wih1[R * H], 32 + 8 * hi4);
            whh[g][0] = load_hi(&Whh1[R * H], 8 * hi4);
            whh[g][1] = load_hi(&Whh1[R * H], 32 + 8 * hi4);
            bias[g] = bih1[R] + bhh1[R];
        }
        const float fcwr = fcw[u];
        __syncthreads();   // prolog barrier

        float c = 0.f;
        auto stepL1 = [&](int s, int par) {
            if (s >= 1) {
                // computes t = s-1: inputs h0(s-1) [buf par^1], h1(s-2) [buf par]
                const s8v gf0 = *(const s8v*)&h0[par ^ 1][bm][8 * hi4];
                const s8v gf1 = *(const s8v*)&h0[par ^ 1][bm][8 * (4 + hi4)];
                const s8v hf0 = *(const s8v*)&h1[par][bm][8 * hi4];
                const s8v hf1 = *(const s8v*)&h1[par][bm][8 * (4 + hi4)];

                f4v a[4], b[4];
                __builtin_amdgcn_s_setprio(1);
                #pragma unroll
                for (int g = 0; g < 4; ++g) {
                    f4v av = {bias[g], bias[g], bias[g], bias[g]};
                    av = mfma_(gf0, wgh[g][0], av);
                    a[g] = mfma_(gf1, wgh[g][1], av);
                    f4v bv = {0.f, 0.f, 0.f, 0.f};
                    bv = mfma_(hf0, whh[g][0], bv);
                    b[g] = mfma_(hf1, whh[g][1], bv);
                }
                __builtin_amdgcn_s_setprio(0);
                const float gi = sig_(a[0][0] + b[0][0]);
                const float gf = sig_(a[1][0] + b[1][0]);
                const float gg = tanh_(a[2][0] + b[2][0]);
                const float go = sig_(a[3][0] + b[3][0]);
                c = gf * c + gi * gg;
                const float hv = go * tanh_(c);
                if (s < T) {
                    h1[par ^ 1][hi4][u] = (unsigned short)cvtpk(hv, hv);
                } else {
                    part[wl][lane] = hv * fcwr;   // fc-head partial from fp32 h
                }
            }
            bar_lds();
        };

        #pragma unroll 1
        for (int s = 0; s < T; s += 2) {       // T even
            stepL1(s,     0);
            stepL1(s + 1, 1);
        }
        stepL1(T, 0);   // tail: computes t=T-1 -> part
    }

    __syncthreads();   // part[] visible (full barrier, drains everything)

    // ---- fc head: out[b] = sum_u h1(T-1)[b][u]*fcw[u] + fcb ----
    if (tid < 64) {
        float v = part[0][lane] + part[1][lane] + part[2][lane] + part[3][lane];
        v += __shfl_xor(v, 1);
        v += __shfl_xor(v, 2);
        v += __shfl_xor(v, 4);
        v += __shfl_xor(v, 8);
        if (j == 0) out[b0 + hi4] = v + fcb[0];
    }
}

extern "C" void kernel_launch(void* const* d_in, const int* in_sizes, int n_in,
                              void* d_out, int out_size, void* d_ws, size_t ws_size,
                              hipStream_t stream) {
    const float* x    = (const float*)d_in[0];
    const float* Wih0 = (const float*)d_in[1];
    const float* Whh0 = (const float*)d_in[2];
    const float* bih0 = (const float*)d_in[3];
    const float* bhh0 = (const float*)d_in[4];
    const float* Wih1 = (const float*)d_in[5];
    const float* Whh1 = (const float*)d_in[6];
    const float* bih1 = (const float*)d_in[7];
    const float* bhh1 = (const float*)d_in[8];
    const float* fcw  = (const float*)d_in[9];
    const float* fcb  = (const float*)d_in[10];
    float* out = (float*)d_out;

    const int B = out_size;                 // 1024
    const int T = in_sizes[0] / (B * F);    // 512

    dim3 grid(B / NB), block(NT);
    hipLaunchKernelGGL(lstm_v16, grid, block, 0, stream,
                       x, Wih0, Whh0, bih0, bhh0,
                       Wih1, Whh1, bih1, bhh1, fcw, fcb,
                       out, T, B);
}